// Round 5
// baseline (156.608 us; speedup 1.0000x reference)
//
#include <hip/hip_runtime.h>
#include <hip/hip_bf16.h>

// LSTM cell fused kernel for MI355X (gfx950) — round 5: chunk-pipelined
// ds_reads with counted lgkmcnt (m201 "derived waits"), 2 barriers/tile.
// stacked = [x|prevh] @ [Wx;Wh] + bx  -> gates -> nexth, nextc
// GEMM: M=8192, N=4096 (4 gates x 1024 states), K=2048, bf16 16x16x32 MFMA.
//
// Geometry: 256x256 tile, BK=64, 8 waves (2M x 4N), per-wave 128x64.
// LDS 128 KiB: A ring 4 half-slots [0,64K), B ring [64K,128K);
// half (tile t, p) at slot 2*(t&1)+p.
//
// Per-tile schedule (chunks pipelined one ahead of MFMA):
//   C0: bf[g0-3]x2 (8 reads) + af01 -> afX (4)   [12 reads]
//   C1: af23 -> afY (4)
//   SA(t+1) x2 (4 gloads)
//   lgkm(4)  -> C0 done, C1 in flight;  M0: m01 x g0-3 x kf (16 MFMA)
//   C2: af45 -> afX (4)          [WAR on afX ok: issued after M0]
//   lgkm(4)  -> C1 done, C2 drains under M1;  M1: m23 (16 MFMA)
//   MID-BARRIER   [every wave passed lgkm(4)>=C0 => all B LDS-reads retired;
//                  M2/M3 consume bf from REGISTERS]
//   SB(t+2) x2 (4 gloads)  [B(t+2) slot == B(t) slot: gated by mid-barrier]
//   C3: af67 -> afY (4)
//   lgkm(4)  -> C2 done;  M2: m45 (16 MFMA)
//   lgkm(0)  -> C3 done;  M3: m67 (16 MFMA)
//   vmcnt(4) -> queue oldest-first: SB(t+1)[4] SA(t+1)[4] SB(t+2)[4];
//              confirms everything tile t+1 reads; 4 stay in flight.
//   END-BARRIER
// lgkm counting is exact: DS ops complete in-order per wave; global_load_lds
// increments vmcnt only. sched_barrier(0) after every counted wait (rule 18).
//
// T2 swizzle both-sides (verified: bank conflicts = 0), XCD chunking,
// gate-permuted Wt, lane-local epilogue: unchanged.
//
// ws layout: A_bf16 [8192][2048] (32MB) | Wt_bf16 [4096 perm][2048] (16MB)

#define BATCH   8192
#define SDIM    1024
#define KDIM    2048
#define NT      32      // K-tiles of 64

typedef __attribute__((ext_vector_type(8))) short s16x8;
typedef __attribute__((ext_vector_type(4))) float f32x4;

__device__ __forceinline__ void gload16(const void* g, void* l) {
    __builtin_amdgcn_global_load_lds((const __attribute__((address_space(1))) void*)g,
                                     (__attribute__((address_space(3))) void*)l,
                                     16, 0, 0);
}

__device__ __forceinline__ float fast_sigmoid(float x) {
    return 1.0f / (1.0f + __expf(-x));
}
__device__ __forceinline__ float fast_tanh(float v) {
    float a = fabsf(v);
    float e = __expf(-2.0f * a);
    float t = (1.0f - e) / (1.0f + e);
    return copysignf(t, v);
}

// ---------------- conversion: A = [x | prevh] -> bf16 [8192][2048] ----------
__global__ void convA(const float* __restrict__ x, const float* __restrict__ h,
                      __hip_bfloat16* __restrict__ A) {
    int t = blockIdx.x * blockDim.x + threadIdx.x;
    int e = t << 3;
    int b = e >> 11;
    int k = e & 2047;
    const float* src = (k < 1024) ? (x + (size_t)b * 1024 + k)
                                  : (h + (size_t)b * 1024 + (k - 1024));
    float4 v0 = *(const float4*)(src);
    float4 v1 = *(const float4*)(src + 4);
    union { __hip_bfloat16 b[8]; s16x8 v; } u;
    u.b[0] = __float2bfloat16(v0.x); u.b[1] = __float2bfloat16(v0.y);
    u.b[2] = __float2bfloat16(v0.z); u.b[3] = __float2bfloat16(v0.w);
    u.b[4] = __float2bfloat16(v1.x); u.b[5] = __float2bfloat16(v1.y);
    u.b[6] = __float2bfloat16(v1.z); u.b[7] = __float2bfloat16(v1.w);
    *(s16x8*)(A + e) = u.v;
}

// ---- conversion + transpose + gate-permute: Wt[n'][k] = W[k][n] -----------
// n = gate*1024 + s  ->  n' = (s>>4)*64 + gate*16 + (s&15)
__global__ void convW(const float* __restrict__ Wx, const float* __restrict__ Wh,
                      __hip_bfloat16* __restrict__ Wt) {
    __shared__ float tile[32][33];
    int k0 = blockIdx.x * 32;
    int n0 = blockIdx.y * 32;
    int tx = threadIdx.x;
    int ty = threadIdx.y;
#pragma unroll
    for (int j = 0; j < 4; ++j) {
        int k = k0 + ty + j * 8;
        int n = n0 + tx;
        float v = (k < 1024) ? Wx[(size_t)k * 4096 + n]
                             : Wh[(size_t)(k - 1024) * 4096 + n];
        tile[ty + j * 8][tx] = v;
    }
    __syncthreads();
#pragma unroll
    for (int j = 0; j < 4; ++j) {
        int n = n0 + ty + j * 8;
        int k = k0 + tx;
        int np = ((n & 1023) >> 4) * 64 + (n >> 10) * 16 + (n & 15);
        Wt[(size_t)np * 2048 + k] = __float2bfloat16(tile[tx][ty + j * 8]);
    }
}

// ---------------- fused GEMM + gates ----------------------------------------
__global__ __launch_bounds__(512, 2) void lstm_gemm(
    const __hip_bfloat16* __restrict__ A,    // [8192][2048]
    const __hip_bfloat16* __restrict__ Wt,   // [4096 perm][2048]
    const float* __restrict__ bx,            // [4096]
    const float* __restrict__ prevc,         // [8192][1024]
    float* __restrict__ outh,
    float* __restrict__ outc)
{
    __shared__ __align__(16) char lds[131072];

    const int tid  = threadIdx.x;
    const int lane = tid & 63;
    const int w    = tid >> 6;   // 0..7
    const int wr   = w >> 2;     // 0..1  A-half
    const int wc   = w & 3;      // 0..3  N quarter; B-half = wc>>1
    const int l15  = lane & 15;

    // XCD chunking: 8 chunks of (8 Mtiles x 8 Ntiles).
    const int bid = blockIdx.x;
    const int xcd = bid & 7, j = bid >> 3;
    const int mt = (xcd >> 1) * 8 + (j & 7);     // 0..31
    const int nt = (xcd & 1) * 8 + (j >> 3);     // 0..15
    const int m0 = mt * 256, n0 = nt * 256, S0 = nt * 64;

    // staging: linear gload_lds dest, inverse-swizzled global source.
    const int scol = ((lane & 7) ^ (lane >> 3)) << 3;   // elems
    const __hip_bfloat16* Ag = A  + (size_t)m0 * KDIM;
    const __hip_bfloat16* Bg = Wt + (size_t)n0 * KDIM;

    auto SA = [&](int tt, int p) {
        char* dst = lds + (2 * (tt & 1) + p) * 16384 + w * 1024;
        const __hip_bfloat16* src =
            Ag + (size_t)(p * 128 + w * 8 + (lane >> 3)) * KDIM + tt * 64 + scol;
        gload16(src, dst);
        gload16(src + (size_t)64 * KDIM, dst + 8192);
    };
    auto SB = [&](int tt, int p) {
        char* dst = lds + 65536 + (2 * (tt & 1) + p) * 16384 + w * 1024;
        const __hip_bfloat16* src =
            Bg + (size_t)(p * 128 + w * 8 + (lane >> 3)) * KDIM + tt * 64 + scol;
        gload16(src, dst);
        gload16(src + (size_t)64 * KDIM, dst + 8192);
    };

    f32x4 acc[8][4];
#pragma unroll
    for (int m = 0; m < 8; ++m)
#pragma unroll
        for (int g = 0; g < 4; ++g)
            acc[m][g] = (f32x4)0.0f;

    // prologue: B(0),A(0),B(1) = 12 loads; vmcnt(4) leaves SB(1) in flight.
    SB(0, 0); SB(0, 1); SA(0, 0); SA(0, 1); SB(1, 0); SB(1, 1);
    asm volatile("s_waitcnt vmcnt(4)" ::: "memory");
    __builtin_amdgcn_s_barrier();
    __builtin_amdgcn_sched_barrier(0);

    // read-side swizzle: granule' = (kf*4 + (lane>>4)) ^ (lane&7), bytes<<4
    const int swz0 = (((lane >> 4))     ^ (lane & 7)) << 4;
    const int swz1 = (((lane >> 4) | 4) ^ (lane & 7)) << 4;
    const int brow = (wc & 1) * 64;

    s16x8 afX[2][2], afY[2][2], bf[4][2];

#define LGKM(n)                                             \
    asm volatile("s_waitcnt lgkmcnt(" #n ")" ::: "memory"); \
    __builtin_amdgcn_sched_barrier(0);

#define MBLK(AF, mb)                                                          \
    __builtin_amdgcn_s_setprio(1);                                            \
    _Pragma("unroll")                                                         \
    for (int kf = 0; kf < 2; ++kf)                                            \
        _Pragma("unroll")                                                     \
        for (int mm = 0; mm < 2; ++mm)                                        \
            _Pragma("unroll")                                                 \
            for (int g = 0; g < 4; ++g)                                       \
                acc[(mb) + mm][g] = __builtin_amdgcn_mfma_f32_16x16x32_bf16(  \
                    AF[mm][kf], bf[g][kf], acc[(mb) + mm][g], 0, 0, 0);       \
    __builtin_amdgcn_s_setprio(0);

    for (int t = 0; t < NT; ++t) {
        const char* as = lds + (2 * (t & 1) + wr) * 16384;
        const char* bs = lds + 65536 + (2 * (t & 1) + (wc >> 1)) * 16384;

        // ---- C0: all bf + af rows 0-1 ----
#pragma unroll
        for (int g = 0; g < 4; ++g) {
            bf[g][0] = *(const s16x8*)(bs + (brow + g * 16 + l15) * 128 + swz0);
            bf[g][1] = *(const s16x8*)(bs + (brow + g * 16 + l15) * 128 + swz1);
        }
#pragma unroll
        for (int mm = 0; mm < 2; ++mm) {
            afX[mm][0] = *(const s16x8*)(as + (mm * 16 + l15) * 128 + swz0);
            afX[mm][1] = *(const s16x8*)(as + (mm * 16 + l15) * 128 + swz1);
        }
        // ---- C1: af rows 2-3 ----
#pragma unroll
        for (int mm = 0; mm < 2; ++mm) {
            afY[mm][0] = *(const s16x8*)(as + ((mm + 2) * 16 + l15) * 128 + swz0);
            afY[mm][1] = *(const s16x8*)(as + ((mm + 2) * 16 + l15) * 128 + swz1);
        }
        if (t + 1 < NT) { SA(t + 1, 0); SA(t + 1, 1); }

        LGKM(4);            // C0 done; C1 drains under M0
        MBLK(afX, 0);

        // ---- C2: af rows 4-5 (reuse afX; issued after M0) ----
#pragma unroll
        for (int mm = 0; mm < 2; ++mm) {
            afX[mm][0] = *(const s16x8*)(as + ((mm + 4) * 16 + l15) * 128 + swz0);
            afX[mm][1] = *(const s16x8*)(as + ((mm + 4) * 16 + l15) * 128 + swz1);
        }
        LGKM(4);            // C1 done; C2 drains under M1
        MBLK(afY, 2);

        __builtin_amdgcn_sched_barrier(0);
        __builtin_amdgcn_s_barrier();        // MID: all B LDS-reads retired
        __builtin_amdgcn_sched_barrier(0);

        if (t + 2 < NT) { SB(t + 2, 0); SB(t + 2, 1); }
        // ---- C3: af rows 6-7 (reuse afY) ----
#pragma unroll
        for (int mm = 0; mm < 2; ++mm) {
            afY[mm][0] = *(const s16x8*)(as + ((mm + 6) * 16 + l15) * 128 + swz0);
            afY[mm][1] = *(const s16x8*)(as + ((mm + 6) * 16 + l15) * 128 + swz1);
        }
        LGKM(4);            // C2 done; C3 drains under M2
        MBLK(afX, 4);

        LGKM(0);            // C3 done
        MBLK(afY, 6);

        __builtin_amdgcn_sched_barrier(0);
        if (t + 2 < NT) {
            asm volatile("s_waitcnt vmcnt(4)" ::: "memory");
        } else {
            asm volatile("s_waitcnt vmcnt(0)" ::: "memory");
        }
        __builtin_amdgcn_s_barrier();        // END: tile t+1 slots published
        __builtin_amdgcn_sched_barrier(0);
    }
#undef LGKM
#undef MBLK

    // ---- fused epilogue: 4 gates lane-local ----
    const int st  = S0 + wc * 16 + l15;
    const float b_i = bx[st];
    const float b_f = bx[1024 + st];
    const float b_o = bx[2048 + st];
    const float b_g = bx[3072 + st];
    const int rbase = m0 + wr * 128 + (lane >> 4) * 4;

#pragma unroll
    for (int m = 0; m < 8; ++m) {
#pragma unroll
        for (int q = 0; q < 4; ++q) {
            int row = rbase + m * 16 + q;
            float ib = acc[m][0][q] + b_i;
            float fb = acc[m][1][q] + b_f;
            float ob = acc[m][2][q] + b_o;
            float gb = acc[m][3][q] + b_g;
            float ig = fast_sigmoid(ib);
            float fg = fast_sigmoid(fb);
            float og = fast_sigmoid(ob);
            float gg = fast_tanh(gb);
            float pc = prevc[(size_t)row * SDIM + st];
            float nc = pc * fg + gg * ig;
            float nh = fast_tanh(nc) * og;
            outh[(size_t)row * SDIM + st] = nh;
            outc[(size_t)row * SDIM + st] = nc;
        }
    }
}

extern "C" void kernel_launch(void* const* d_in, const int* in_sizes, int n_in,
                              void* d_out, int out_size, void* d_ws, size_t ws_size,
                              hipStream_t stream) {
    const float* x     = (const float*)d_in[0];
    const float* prevh = (const float*)d_in[1];
    const float* prevc = (const float*)d_in[2];
    const float* Wx    = (const float*)d_in[3];
    const float* bx    = (const float*)d_in[4];
    const float* Wh    = (const float*)d_in[5];

    __hip_bfloat16* Abf = (__hip_bfloat16*)d_ws;
    __hip_bfloat16* Wt  = Abf + (size_t)BATCH * KDIM;   // +32MB

    float* outh = (float*)d_out;
    float* outc = outh + (size_t)BATCH * SDIM;

    hipLaunchKernelGGL(convA, dim3(8192), dim3(256), 0, stream, x, prevh, Abf);
    hipLaunchKernelGGL(convW, dim3(64, 128), dim3(32, 8), 0, stream, Wx, Wh, Wt);
    hipLaunchKernelGGL(lstm_gemm, dim3(512), dim3(512), 0, stream,
                       Abf, Wt, bx, prevc, outh, outc);
}